// Round 8
// baseline (52958.533 us; speedup 1.0000x reference)
//
#include <hip/hip_runtime.h>

// problem dims
#define B_   64
#define T_   800
#define U_   64
#define N_   64
#define KMIX 10
#define H_   512
#define O_   121
#define C4_  2048   // 4*H

// grid layout: (batch-group x column-group) blocks, colg -> XCD slice
#define NB_L0  64   // 8 bq x 8 colg
#define NB_L1  64
#define NB_L2  64
#define NB_OUT 8    // 1 per bq
#define NB_ATT 8    // 1 per bq
#define NBLK  (NB_L0 + NB_L1 + NB_L2 + NB_OUT + NB_ATT)  // 208
#define NTHR  1024  // 16 waves: kh=0 -> k[0,256), kh=1 -> k[256,512)
#define RING  8
#define RB    (RING - 1)
#define FS    8     // ints per flag slot (32B spacing)

#define AL(pp) __hip_atomic_load((pp), __ATOMIC_RELAXED, __HIP_MEMORY_SCOPE_AGENT)

typedef float vf4 __attribute__((ext_vector_type(4)));

struct Params {
  const float* strokes; const float* transcr;
  const float* transcrT;                // [b][n][u] transpose (w2 inner loop)
  const float* W0; const float* b0;
  const float* bd;
  const float* W1; const float* b1;
  const float* W2; const float* b2;
  const float* bo;
  const float4* PR0; const float4* PW0w;
  const float4* PH1; const float4* PR1; const float4* PW1w;
  const float4* PH2; const float4* PR2; const float4* PW2w;
  const float4* PWo; const float4* PWd;
  float* h0r; float* h1r; float* h2r;   // rings [RING][B][H], coherent access
  float* wr;                            // ring [RING][B][N]
  int *h0f, *h1f, *h2f, *wfl, *outf;    // flags [T][8 bq][FS]
  float* outp; float* attp;
};

__device__ __forceinline__ float sigf(float x) { return 1.0f / (1.0f + expf(-x)); }

// quantize a double onto the fp32 grid INCLUDING subnormals, round-half-even.
__device__ __forceinline__ double f32q(double x) {
  double ax = fabs(x);
  if (ax >= 0x1p-126) return (double)(float)x;
  return rint(x * 0x1p149) * 0x1p-149;
}

__device__ __forceinline__ void cstoref(float* p, float v) {
  __hip_atomic_store(p, v, __ATOMIC_RELAXED, __HIP_MEMORY_SCOPE_AGENT);
}

// ---- 16B coherent loads (sc0 sc1 = system scope: bypasses the non-coherent
// per-XCD L2, same visibility class as the 8B agent atomic loads they replace,
// at HALF the coherent-fabric op count per byte). Loads issue back-to-back in
// one asm block; single vmcnt(0) before use. Producer ordering is unchanged
// (ring stores drained by __syncthreads before the flag post).
__device__ __forceinline__ vf4 cld1(const void* p0) {
  vf4 a;
  asm volatile("global_load_dwordx4 %0, %1, off sc0 sc1\n\t"
               "s_waitcnt vmcnt(0)"
               : "=&v"(a) : "v"(p0) : "memory");
  return a;
}
__device__ __forceinline__ void cld2(const void* p0, const void* p1, vf4& a, vf4& b) {
  asm volatile("global_load_dwordx4 %0, %2, off sc0 sc1\n\t"
               "global_load_dwordx4 %1, %3, off sc0 sc1\n\t"
               "s_waitcnt vmcnt(0)"
               : "=&v"(a), "=&v"(b) : "v"(p0), "v"(p1) : "memory");
}
__device__ __forceinline__ void cld3(const void* p0, const void* p1, const void* p2,
                                     vf4& a, vf4& b, vf4& c) {
  asm volatile("global_load_dwordx4 %0, %3, off sc0 sc1\n\t"
               "global_load_dwordx4 %1, %4, off sc0 sc1\n\t"
               "global_load_dwordx4 %2, %5, off sc0 sc1\n\t"
               "s_waitcnt vmcnt(0)"
               : "=&v"(a), "=&v"(b), "=&v"(c)
               : "v"(p0), "v"(p1), "v"(p2) : "memory");
}

// ---- bq-local flags ----
__device__ __forceinline__ int* FP(int* arr, int tt, int bq) {
  return arr + ((size_t)tt * 8 + bq) * FS;
}
__device__ __forceinline__ void waitflag(const int* f, int target) {
  while (__hip_atomic_load(f, __ATOMIC_RELAXED, __HIP_MEMORY_SCOPE_AGENT) < target)
    __builtin_amdgcn_s_sleep(1);
}
__device__ __forceinline__ void postflag(int* f) {
  __hip_atomic_fetch_add(f, 1, __ATOMIC_RELAXED, __HIP_MEMORY_SCOPE_AGENT);
}

// batched coherent stage (1024 threads): 4096 floats (8 x 512 tile) -> LDS.
// One 16B load per thread.
__device__ __forceinline__ void stage4k(float* dstL, const float* src, int t) {
  vf4 v = cld1((const vf4*)src + t);
  *((vf4*)dstL + t) = v;
}
// two tiles fused (one round trip for both; 2 x 16B per thread)
__device__ __forceinline__ void stage4k2(float* d1, const float* s1,
                                         float* d2, const float* s2, int t) {
  vf4 a, b;
  cld2((const vf4*)s1 + t, (const vf4*)s2 + t, a, b);
  *((vf4*)d1 + t) = a;
  *((vf4*)d2 + t) = b;
}
// 512-float stage (w ring row-group): 128 threads x 16B
__device__ __forceinline__ void stage512(float* dstL, const float* src, int t) {
  if (t < 128) {
    vf4 v = cld1((const vf4*)src + t);
    *((vf4*)dstL + t) = v;
  }
}

// z-GEMV core: X from LDS (wave-uniform broadcast), W plain loads (L2-hot).
// Layout (pack_k): a wave's 64 lanes read 1KB contiguous per load instruction.
__device__ __forceinline__ void dot4gl(const float* Xl,
                                       const float4* __restrict__ W,
                                       int k4, int col, float acc[4]) {
  const float4* X = (const float4*)Xl;
  #pragma unroll 2
  for (int kk = 0; kk < k4; ++kk) {
    float4 xv = X[kk];
    #pragma unroll
    for (int g = 0; g < 4; ++g) {
      float4 wv = W[kk * C4_ + g * H_ + col];
      acc[g] = fmaf(xv.x, wv.x, acc[g]);
      acc[g] = fmaf(xv.y, wv.y, acc[g]);
      acc[g] = fmaf(xv.z, wv.z, acc[g]);
      acc[g] = fmaf(xv.w, wv.w, acc[g]);
    }
  }
}

__device__ __forceinline__ float dot1l(const float* Xl,
                                       const float4* __restrict__ W,
                                       int k4, int stride) {
  const float4* X = (const float4*)Xl;
  float a = 0.0f;
  #pragma unroll 4
  for (int kk = 0; kk < k4; ++kk) {
    float4 xv = X[kk];
    float4 wv = W[kk * stride];
    a = fmaf(xv.x, wv.x, a); a = fmaf(xv.y, wv.y, a);
    a = fmaf(xv.z, wv.z, a); a = fmaf(xv.w, wv.w, a);
  }
  return a;
}

// repack row-major (K x C, leading dim ld) into k-interleaved float4 layout
__global__ void pack_k(const float* __restrict__ src, float* __restrict__ dst,
                       int K, int C, int ld) {
  int idx = blockIdx.x * 256 + threadIdx.x;
  if (idx >= K * C) return;
  int k = idx / C, c = idx - k * C;
  dst[(size_t)(k >> 2) * C * 4 + (size_t)c * 4 + (k & 3)] = src[(size_t)k * ld + c];
}

// transcriptions [b][u][n] -> [b][n][u] (w2's u-loop becomes contiguous float4s)
__global__ void pack_t(const float* __restrict__ src, float* __restrict__ dst) {
  int idx = blockIdx.x * 256 + threadIdx.x;
  if (idx >= B_ * U_ * N_) return;
  int b = idx >> 12, r = idx & 4095;
  int u = r >> 6, n = r & 63;
  dst[((size_t)b * N_ + n) * U_ + u] = src[((size_t)b * U_ + u) * N_ + n];
}

__global__ __launch_bounds__(NTHR, 4)
void net_kernel(Params p) {
  const int q = blockIdx.x;
  const int t = threadIdx.x;

  __shared__ float  s_buf[12288];   // staged X tiles + k-split reduction area
  __shared__ float  s_y[16][32];
  __shared__ float  s_k2[16][10];
  __shared__ float  s_kap[16][10];
  __shared__ double s_wf[16][66];

  if (q < NB_L0) {                                   // ---- layer 0 ----
    const int bq = q >> 3, colg = q & 7;
    const int kh = t >> 9;            // k-half: 0 -> k[0,256), 1 -> k[256,512)
    const int bl = (t >> 6) & 7, cl = t & 63;
    const int b = bq * 8 + bl, col = colg * 64 + cl;
    float* sh = s_buf;                // h0(i-1): 8 x 512
    float* sw = s_buf + 4096;         // w(i-1):  8 x 64
    float4* s_red = (float4*)(s_buf + 4608);  // 512 x float4 partials
    float creg = 0.0f;
    for (int i = 0; i < T_; ++i) {
      if (t == 0) {
        if (i >= 1) waitflag(FP(p.h0f, i - 1, bq), 8);
        if (i >= 8) waitflag(FP(p.outf, i - 8, bq), 1);
      }
      __syncthreads();
      const int slp = (i - 1) & RB;
      stage4k(sh, &p.h0r[((size_t)slp * B_ + bq * 8) * H_], t);
      float acc[4] = {0.f, 0.f, 0.f, 0.f};
      if (kh == 0) {
        const float* xs = &p.strokes[(b * T_ + i) * 3];
        float x0 = xs[0], x1 = xs[1], x2 = xs[2];
        #pragma unroll
        for (int g = 0; g < 4; ++g) {
          int cg = g * H_ + col;
          acc[g] = p.b0[cg] + x0 * p.W0[cg] + x1 * p.W0[C4_ + cg] + x2 * p.W0[2 * C4_ + cg];
        }
      }
      __syncthreads();
      dot4gl(sh + bl * H_ + kh * 256, p.PR0 + (size_t)kh * 64 * C4_, 64, col, acc);
      if (t == 0 && i >= 1) waitflag(FP(p.wfl, i - 1, bq), 1);
      __syncthreads();
      stage512(sw, &p.wr[((size_t)slp * B_ + bq * 8) * N_], t);
      __syncthreads();
      dot4gl(sw + bl * N_ + kh * 32, p.PW0w + (size_t)kh * 8 * C4_, 8, col, acc);
      if (kh) { float4 r; r.x = acc[0]; r.y = acc[1]; r.z = acc[2]; r.w = acc[3]; s_red[t - 512] = r; }
      __syncthreads();
      if (!kh) {
        float4 r = s_red[t];
        float cn = sigf(acc[1] + r.y) * creg + sigf(acc[0] + r.x) * tanhf(acc[2] + r.z);
        float hn = sigf(acc[3] + r.w) * tanhf(cn);
        creg = cn;
        cstoref(&p.h0r[((size_t)(i & RB) * B_ + b) * H_ + col], hn);
      }
      __syncthreads();
      if (t == 0) postflag(FP(p.h0f, i, bq));
    }
  } else if (q < NB_L0 + NB_L1) {                    // ---- layer 1 ----
    const int qq = q - NB_L0;
    const int bq = qq >> 3, colg = qq & 7;
    const int kh = t >> 9;
    const int bl = (t >> 6) & 7, cl = t & 63;
    const int b = bq * 8 + bl, col = colg * 64 + cl;
    float* sh0 = s_buf;               // h0(tt)
    float* sh1 = s_buf + 4096;        // h1(tt-1)
    float* sw  = s_buf + 8192;        // w(tt)
    float4* s_red = (float4*)(s_buf + 8704);
    float creg = 0.0f;
    for (int tt = 0; tt < T_; ++tt) {
      if (t == 0) {
        waitflag(FP(p.h0f, tt, bq), 8);
        if (tt >= 1) waitflag(FP(p.h1f, tt - 1, bq), 8);
        if (tt >= 7) waitflag(FP(p.outf, tt - 7, bq), 1);
      }
      __syncthreads();
      const int sl = tt & RB, slp = (tt - 1) & RB;
      stage4k2(sh0, &p.h0r[((size_t)sl * B_ + bq * 8) * H_],
               sh1, &p.h1r[((size_t)slp * B_ + bq * 8) * H_], t);
      float acc[4] = {0.f, 0.f, 0.f, 0.f};
      if (kh == 0) {
        const float* xs = &p.strokes[(b * T_ + tt) * 3];
        float x0 = xs[0], x1 = xs[1], x2 = xs[2];
        #pragma unroll
        for (int g = 0; g < 4; ++g) {
          int cg = g * H_ + col;
          acc[g] = p.b1[cg] + x0 * p.W1[576 * C4_ + cg] + x1 * p.W1[577 * C4_ + cg]
                            + x2 * p.W1[578 * C4_ + cg];
        }
      }
      __syncthreads();
      dot4gl(sh0 + bl * H_ + kh * 256, p.PH1 + (size_t)kh * 64 * C4_, 64, col, acc);
      dot4gl(sh1 + bl * H_ + kh * 256, p.PR1 + (size_t)kh * 64 * C4_, 64, col, acc);
      if (t == 0) waitflag(FP(p.wfl, tt, bq), 1);
      __syncthreads();
      stage512(sw, &p.wr[((size_t)sl * B_ + bq * 8) * N_], t);
      __syncthreads();
      dot4gl(sw + bl * N_ + kh * 32, p.PW1w + (size_t)kh * 8 * C4_, 8, col, acc);
      if (kh) { float4 r; r.x = acc[0]; r.y = acc[1]; r.z = acc[2]; r.w = acc[3]; s_red[t - 512] = r; }
      __syncthreads();
      if (!kh) {
        float4 r = s_red[t];
        float cn = sigf(acc[1] + r.y) * creg + sigf(acc[0] + r.x) * tanhf(acc[2] + r.z);
        float hn = sigf(acc[3] + r.w) * tanhf(cn);
        creg = cn;
        cstoref(&p.h1r[((size_t)sl * B_ + b) * H_ + col], hn);
      }
      __syncthreads();
      if (t == 0) postflag(FP(p.h1f, tt, bq));
    }
  } else if (q < NB_L0 + NB_L1 + NB_L2) {            // ---- layer 2 ----
    const int qq = q - NB_L0 - NB_L1;
    const int bq = qq >> 3, colg = qq & 7;
    const int kh = t >> 9;
    const int bl = (t >> 6) & 7, cl = t & 63;
    const int b = bq * 8 + bl, col = colg * 64 + cl;
    float* sh1 = s_buf;               // h1(tt)
    float* sh2 = s_buf + 4096;        // h2(tt-1)
    float* sw  = s_buf + 8192;        // w(tt)
    float4* s_red = (float4*)(s_buf + 8704);
    float creg = 0.0f;
    for (int tt = 0; tt < T_; ++tt) {
      if (t == 0) {
        waitflag(FP(p.h1f, tt, bq), 8);
        waitflag(FP(p.wfl, tt, bq), 1);
        if (tt >= 1) waitflag(FP(p.h2f, tt - 1, bq), 8);
        if (tt >= 6) waitflag(FP(p.outf, tt - 6, bq), 1);
      }
      __syncthreads();
      const int sl = tt & RB, slp = (tt - 1) & RB;
      stage4k2(sh1, &p.h1r[((size_t)sl * B_ + bq * 8) * H_],
               sh2, &p.h2r[((size_t)slp * B_ + bq * 8) * H_], t);
      stage512(sw, &p.wr[((size_t)sl * B_ + bq * 8) * N_], t);
      float acc[4] = {0.f, 0.f, 0.f, 0.f};
      if (kh == 0) {
        const float* xs = &p.strokes[(b * T_ + tt) * 3];
        float x0 = xs[0], x1 = xs[1], x2 = xs[2];
        #pragma unroll
        for (int g = 0; g < 4; ++g) {
          int cg = g * H_ + col;
          acc[g] = p.b2[cg] + x0 * p.W2[576 * C4_ + cg] + x1 * p.W2[577 * C4_ + cg]
                            + x2 * p.W2[578 * C4_ + cg];
        }
      }
      __syncthreads();
      dot4gl(sh1 + bl * H_ + kh * 256, p.PH2 + (size_t)kh * 64 * C4_, 64, col, acc);
      dot4gl(sw + bl * N_ + kh * 32, p.PW2w + (size_t)kh * 8 * C4_, 8, col, acc);
      dot4gl(sh2 + bl * H_ + kh * 256, p.PR2 + (size_t)kh * 64 * C4_, 64, col, acc);
      if (kh) { float4 r; r.x = acc[0]; r.y = acc[1]; r.z = acc[2]; r.w = acc[3]; s_red[t - 512] = r; }
      __syncthreads();
      if (!kh) {
        float4 r = s_red[t];
        float cn = sigf(acc[1] + r.y) * creg + sigf(acc[0] + r.x) * tanhf(acc[2] + r.z);
        float hn = sigf(acc[3] + r.w) * tanhf(cn);
        creg = cn;
        cstoref(&p.h2r[((size_t)sl * B_ + b) * H_ + col], hn);
      }
      __syncthreads();
      if (t == 0) postflag(FP(p.h2f, tt, bq));
    }
  } else if (q < NB_L0 + NB_L1 + NB_L2 + NB_OUT) {   // ---- output head ----
    const int bq = q - NB_L0 - NB_L1 - NB_L2;
    const int kh = t >> 9;
    const int bl = (t >> 6) & 7, ol = t & 63;
    const int b = bq * 8 + bl;
    const int oo1 = ol;
    const bool v2 = (ol < O_ - 64);
    const int oo2 = v2 ? (ol + 64) : 0;
    float* sx0 = s_buf;
    float* sx1 = s_buf + 4096;
    float* sx2 = s_buf + 8192;
    float* s_red = (float*)s_wf;      // 512 x 2 partials (out block doesn't use s_wf)
    for (int tt = 0; tt < T_; ++tt) {
      if (t == 0) {
        waitflag(FP(p.h0f, tt, bq), 8);
        waitflag(FP(p.h1f, tt, bq), 8);
        waitflag(FP(p.h2f, tt, bq), 8);
      }
      __syncthreads();
      const int sl = tt & RB;
      {  // 3-tile fused stage: one LLC round trip (3 x 16B back-to-back loads)
        vf4 a, c, e;
        cld3((const vf4*)&p.h0r[((size_t)sl * B_ + bq * 8) * H_] + t,
             (const vf4*)&p.h1r[((size_t)sl * B_ + bq * 8) * H_] + t,
             (const vf4*)&p.h2r[((size_t)sl * B_ + bq * 8) * H_] + t, a, c, e);
        *((vf4*)sx0 + t) = a;
        *((vf4*)sx1 + t) = c;
        *((vf4*)sx2 + t) = e;
      }
      __syncthreads();
      const float* X0 = sx0 + bl * H_ + kh * 256;
      const float* X1 = sx1 + bl * H_ + kh * 256;
      const float* X2 = sx2 + bl * H_ + kh * 256;
      const size_t khO = (size_t)(kh * 64) * O_;
      float a1v = kh ? 0.0f : p.bo[oo1];
      a1v += dot1l(X0, p.PWo + khO + oo1, 64, O_);
      a1v += dot1l(X1, p.PWo + (size_t)128 * O_ + khO + oo1, 64, O_);
      a1v += dot1l(X2, p.PWo + (size_t)256 * O_ + khO + oo1, 64, O_);
      float a2v = kh ? 0.0f : p.bo[oo2];
      a2v += dot1l(X0, p.PWo + khO + oo2, 64, O_);
      a2v += dot1l(X1, p.PWo + (size_t)128 * O_ + khO + oo2, 64, O_);
      a2v += dot1l(X2, p.PWo + (size_t)256 * O_ + khO + oo2, 64, O_);
      if (kh) { s_red[(t - 512) * 2] = a1v; s_red[(t - 512) * 2 + 1] = a2v; }
      __syncthreads();
      if (!kh) {
        a1v += s_red[t * 2];
        a2v += s_red[t * 2 + 1];
        __builtin_nontemporal_store(a1v, &p.outp[(size_t)(b * T_ + tt) * O_ + oo1]);
        if (v2) __builtin_nontemporal_store(a2v, &p.outp[(size_t)(b * T_ + tt) * O_ + oo2]);
      }
      __syncthreads();
      if (t == 0) postflag(FP(p.outf, tt, bq));
    }
  } else {                                           // ---- attention (1 per bq) ----
    const int bq = q - NB_L0 - NB_L1 - NB_L2 - NB_OUT;
    const int lb = t >> 7, s = t & 127;   // 8 batches x 128 threads
    const int ub = bq * 8 + lb;
    for (int z = t; z < 80; z += NTHR) ((float*)s_kap)[z] = 0.0f;
    __syncthreads();
    for (int tt = 0; tt < T_; ++tt) {
      if (t == 0) waitflag(FP(p.h0f, tt, bq), 8);
      __syncthreads();
      const int sl = tt & RB;
      {  // stage 8 rows (4096 floats) of h0(tt): one 16B load per thread
        vf4 v = cld1((const vf4*)&p.h0r[((size_t)sl * B_ + bq * 8) * H_] + t);
        *((vf4*)s_buf + t) = v;
      }
      __syncthreads();
      if (s < 30) {
        float a = p.bd[s] + dot1l(s_buf + lb * H_, p.PWd + s, 128, 30);
        float y = expf(a);
        s_y[lb][s] = y;
        if (s >= 20) {
          float k2 = s_kap[lb][s - 20] + y;
          s_kap[lb][s - 20] = k2;
          s_k2[lb][s - 20] = k2;
        }
      }
      __syncthreads();
      // numpy-fp32 underflow-exact wfull (validated): one u per thread
      if (s < U_ + 1) {
        const int u = s;
        double wf = 0.0;
        #pragma unroll
        for (int k = 0; k < KMIX; ++k) {
          float d32 = s_k2[lb][k] - (float)(u + 1);
          float sq  = d32 * d32;
          float m   = -(s_y[lb][10 + k] * sq);
          double e  = exp((double)m);
          double e32 = (e < 0x1p-126) ? 0.0 : (double)(float)e;
          wf += f32q((double)s_y[lb][k] * e32);
        }
        s_wf[lb][u] = wf;
      }
      __syncthreads();
      if (s < N_) {  // w2: one n per thread, contiguous float4 u-loads (transcrT)
        const float4* Tp = (const float4*)&p.transcrT[((size_t)ub * N_ + s) * U_];
        float a2 = 0.f;
        #pragma unroll
        for (int kk = 0; kk < 16; ++kk) {
          float4 tv = Tp[kk];
          a2 = fmaf((float)s_wf[lb][4 * kk],     tv.x, a2);
          a2 = fmaf((float)s_wf[lb][4 * kk + 1], tv.y, a2);
          a2 = fmaf((float)s_wf[lb][4 * kk + 2], tv.z, a2);
          a2 = fmaf((float)s_wf[lb][4 * kk + 3], tv.w, a2);
        }
        cstoref(&p.wr[((size_t)sl * B_ + ub) * N_ + s], a2);
      }
      __syncthreads();
      if (t == 0) postflag(FP(p.wfl, tt, bq));
      // argmax off the critical path (after wfl posted)
      if (s == 127) {
        int am = 0; double bv = s_wf[lb][0];
        for (int u = 1; u < U_ + 1; ++u) {
          double v = s_wf[lb][u];
          if (v > bv) { bv = v; am = u; }
        }
        __builtin_nontemporal_store((float)am, &p.attp[ub * T_ + tt]);
      }
    }
  }
}

extern "C" void kernel_launch(void* const* d_in, const int* in_sizes, int n_in,
                              void* d_out, int out_size, void* d_ws, size_t ws_size,
                              hipStream_t stream) {
  (void)in_sizes; (void)n_in; (void)out_size; (void)ws_size;
  const float* strokes = (const float*)d_in[0];
  const float* transcr = (const float*)d_in[1];
  const float* W0 = (const float*)d_in[2];
  const float* R0 = (const float*)d_in[3];
  const float* b0 = (const float*)d_in[4];
  const float* Wd = (const float*)d_in[5];
  const float* bd = (const float*)d_in[6];
  const float* W1 = (const float*)d_in[7];
  const float* R1 = (const float*)d_in[8];
  const float* b1 = (const float*)d_in[9];
  const float* W2 = (const float*)d_in[10];
  const float* R2 = (const float*)d_in[11];
  const float* b2 = (const float*)d_in[12];
  const float* Wo = (const float*)d_in[13];
  const float* bo = (const float*)d_in[14];

  float* ws = (float*)d_ws;
  size_t off = 0;
  float* h0r = ws + off; off += (size_t)RING * B_ * H_;
  float* h1r = ws + off; off += (size_t)RING * B_ * H_;
  float* h2r = ws + off; off += (size_t)RING * B_ * H_;
  float* wr  = ws + off; off += (size_t)RING * B_ * N_;
  const size_t FLAGN = (size_t)T_ * 8 * FS;
  int* h0f  = (int*)(ws + off); off += FLAGN;
  int* h1f  = (int*)(ws + off); off += FLAGN;
  int* h2f  = (int*)(ws + off); off += FLAGN;
  int* wfl  = (int*)(ws + off); off += FLAGN;
  int* outf = (int*)(ws + off); off += FLAGN;
  size_t stateFloats = off;
  float* PR0  = ws + off; off += (size_t)512 * 2048;
  float* PW0w = ws + off; off += (size_t)64 * 2048;
  float* PH1  = ws + off; off += (size_t)512 * 2048;
  float* PR1  = ws + off; off += (size_t)512 * 2048;
  float* PW1w = ws + off; off += (size_t)64 * 2048;
  float* PH2  = ws + off; off += (size_t)512 * 2048;
  float* PR2  = ws + off; off += (size_t)512 * 2048;
  float* PW2w = ws + off; off += (size_t)64 * 2048;
  float* PWo  = ws + off; off += (size_t)1536 * 121;
  float* PWd  = ws + off; off += (size_t)512 * 30;
  float* TT   = ws + off; off += (size_t)B_ * U_ * N_;

  // zero rings + flags (ws is poisoned 0xAA before every call)
  (void)hipMemsetAsync(d_ws, 0, stateFloats * sizeof(float), stream);

  auto packl = [&](const float* src, float* dst, int K, int C, int ld) {
    int n = K * C;
    pack_k<<<dim3((n + 255) / 256), dim3(256), 0, stream>>>(src, dst, K, C, ld);
  };
  packl(R0, PR0, 512, 2048, 2048);
  packl(W0 + 3 * 2048, PW0w, 64, 2048, 2048);
  packl(W1, PH1, 512, 2048, 2048);
  packl(R1, PR1, 512, 2048, 2048);
  packl(W1 + 512 * 2048, PW1w, 64, 2048, 2048);
  packl(W2, PH2, 512, 2048, 2048);
  packl(R2, PR2, 512, 2048, 2048);
  packl(W2 + 512 * 2048, PW2w, 64, 2048, 2048);
  packl(Wo, PWo, 1536, 121, 121);
  packl(Wd, PWd, 512, 30, 30);
  pack_t<<<dim3((B_ * U_ * N_ + 255) / 256), dim3(256), 0, stream>>>(transcr, TT);

  Params p;
  p.strokes = strokes; p.transcr = transcr; p.transcrT = TT;
  p.W0 = W0; p.b0 = b0; p.bd = bd;
  p.W1 = W1; p.b1 = b1; p.W2 = W2; p.b2 = b2; p.bo = bo;
  p.PR0 = (const float4*)PR0; p.PW0w = (const float4*)PW0w;
  p.PH1 = (const float4*)PH1; p.PR1 = (const float4*)PR1; p.PW1w = (const float4*)PW1w;
  p.PH2 = (const float4*)PH2; p.PR2 = (const float4*)PR2; p.PW2w = (const float4*)PW2w;
  p.PWo = (const float4*)PWo; p.PWd = (const float4*)PWd;
  p.h0r = h0r; p.h1r = h1r; p.h2r = h2r; p.wr = wr;
  p.h0f = h0f; p.h1f = h1f; p.h2f = h2f; p.wfl = wfl; p.outf = outf;
  p.outp = (float*)d_out;
  p.attp = (float*)d_out + (size_t)B_ * T_ * O_;

  void* args[] = { (void*)&p };
  (void)hipLaunchCooperativeKernel((const void*)net_kernel, dim3(NBLK), dim3(NTHR),
                                   args, 0, stream);
}

// Round 9
// 51441.235 us; speedup vs baseline: 1.0295x; 1.0295x over previous
//
#include <hip/hip_runtime.h>

// problem dims
#define B_   64
#define T_   800
#define U_   64
#define N_   64
#define KMIX 10
#define H_   512
#define O_   121
#define C4_  2048   // 4*H

// grid layout: (batch-group x column-group) blocks, colg -> XCD slice
#define NB_L0  64   // 8 bq x 8 colg
#define NB_L1  64
#define NB_L2  64
#define NB_OUT 8    // 1 per bq
#define NB_ATT 8    // 1 per bq
#define NBLK  (NB_L0 + NB_L1 + NB_L2 + NB_OUT + NB_ATT)  // 208
#define NTHR  512   // 8 waves; full-k dots (no k-split reduction phases)
#define RING  8
#define RB    (RING - 1)
#define FS    8     // ints per flag slot (32B spacing)

typedef float vf4 __attribute__((ext_vector_type(4)));

struct Params {
  const float* strokes; const float* transcr;
  const float* transcrT;                // [b][n][u] transpose (w2 inner loop)
  const float* W0; const float* b0;
  const float* bd;
  const float* W1; const float* b1;
  const float* W2; const float* b2;
  const float* bo;
  const float4* PR0; const float4* PW0w;
  const float4* PH1; const float4* PR1; const float4* PW1w;
  const float4* PH2; const float4* PR2; const float4* PW2w;
  const float4* PWo; const float4* PWd;
  float* h0r; float* h1r; float* h2r;   // rings [RING][B][H], coherent access
  float* wr;                            // ring [RING][B][N]
  int *h0f, *h1f, *h2f, *wfl, *outf;    // flags [T][8 bq][FS]
  float* outp; float* attp;
};

__device__ __forceinline__ float sigf(float x) { return 1.0f / (1.0f + expf(-x)); }

// quantize a double onto the fp32 grid INCLUDING subnormals, round-half-even.
__device__ __forceinline__ double f32q(double x) {
  double ax = fabs(x);
  if (ax >= 0x1p-126) return (double)(float)x;
  return rint(x * 0x1p149) * 0x1p-149;
}

__device__ __forceinline__ void cstoref(float* p, float v) {
  __hip_atomic_store(p, v, __ATOMIC_RELAXED, __HIP_MEMORY_SCOPE_AGENT);
}

// ---- 16B coherent loads (sc0 sc1: bypass non-coherent L2; r8-verified class)
__device__ __forceinline__ vf4 cld1(const void* p0) {
  vf4 a;
  asm volatile("global_load_dwordx4 %0, %1, off sc0 sc1\n\t"
               "s_waitcnt vmcnt(0)"
               : "=&v"(a) : "v"(p0) : "memory");
  return a;
}
__device__ __forceinline__ void cld2(const void* p0, const void* p1, vf4& a, vf4& b) {
  asm volatile("global_load_dwordx4 %0, %2, off sc0 sc1\n\t"
               "global_load_dwordx4 %1, %3, off sc0 sc1\n\t"
               "s_waitcnt vmcnt(0)"
               : "=&v"(a), "=&v"(b) : "v"(p0), "v"(p1) : "memory");
}
__device__ __forceinline__ void cld3(const void* p0, const void* p1, const void* p2,
                                     vf4& a, vf4& b, vf4& c) {
  asm volatile("global_load_dwordx4 %0, %3, off sc0 sc1\n\t"
               "global_load_dwordx4 %1, %4, off sc0 sc1\n\t"
               "global_load_dwordx4 %2, %5, off sc0 sc1\n\t"
               "s_waitcnt vmcnt(0)"
               : "=&v"(a), "=&v"(b), "=&v"(c)
               : "v"(p0), "v"(p1), "v"(p2) : "memory");
}
__device__ __forceinline__ void cld4(const void* p0, const void* p1, const void* p2,
                                     const void* p3, vf4& a, vf4& b, vf4& c, vf4& d) {
  asm volatile("global_load_dwordx4 %0, %4, off sc0 sc1\n\t"
               "global_load_dwordx4 %1, %5, off sc0 sc1\n\t"
               "global_load_dwordx4 %2, %6, off sc0 sc1\n\t"
               "global_load_dwordx4 %3, %7, off sc0 sc1\n\t"
               "s_waitcnt vmcnt(0)"
               : "=&v"(a), "=&v"(b), "=&v"(c), "=&v"(d)
               : "v"(p0), "v"(p1), "v"(p2), "v"(p3) : "memory");
}

// ---- bq-local flags ----
__device__ __forceinline__ int* FP(int* arr, int tt, int bq) {
  return arr + ((size_t)tt * 8 + bq) * FS;
}
__device__ __forceinline__ void waitflag(const int* f, int target) {
  while (__hip_atomic_load(f, __ATOMIC_RELAXED, __HIP_MEMORY_SCOPE_AGENT) < target)
    __builtin_amdgcn_s_sleep(1);
}
__device__ __forceinline__ void postflag(int* f) {
  __hip_atomic_fetch_add(f, 1, __ATOMIC_RELAXED, __HIP_MEMORY_SCOPE_AGENT);
}

// 4096-float tile -> LDS, 512 threads x 2x16B (one LLC round trip)
__device__ __forceinline__ void stage4k(float* dstL, const float* src, int t) {
  vf4 a, b;
  cld2((const vf4*)src + t, (const vf4*)src + 512 + t, a, b);
  *((vf4*)dstL + t) = a;
  *((vf4*)dstL + 512 + t) = b;
}
// two 4096-float tiles fused, 4x16B per thread (one round trip)
__device__ __forceinline__ void stage4k2(float* d1, const float* s1,
                                         float* d2, const float* s2, int t) {
  vf4 a, b, c, d;
  cld4((const vf4*)s1 + t, (const vf4*)s1 + 512 + t,
       (const vf4*)s2 + t, (const vf4*)s2 + 512 + t, a, b, c, d);
  *((vf4*)d1 + t) = a;
  *((vf4*)d1 + 512 + t) = b;
  *((vf4*)d2 + t) = c;
  *((vf4*)d2 + 512 + t) = d;
}
// 512-float w tile, all-thread variant (t < 128)
__device__ __forceinline__ void stage512(float* dstL, const float* src, int t) {
  if (t < 128) {
    vf4 v = cld1((const vf4*)src + t);
    *((vf4*)dstL + t) = v;
  }
}
// 512-float w tile, wave0-only: lane0 polls wfl first, then the wave stages in
// lockstep (2x16B per lane) -- hides the att hop under the other waves' dotR
// without an extra barrier phase.
__device__ __forceinline__ void stage512w(float* dstL, const float* src, int lane) {
  vf4 a, b;
  cld2((const vf4*)src + lane, (const vf4*)src + 64 + lane, a, b);
  *((vf4*)dstL + lane) = a;
  *((vf4*)dstL + 64 + lane) = b;
}

// z-GEMV core (round-0 verbatim): X from LDS wave-uniform broadcast, W via
// pack_k layout -> a wave's 64 lanes read 1KB contiguous per load instruction.
__device__ __forceinline__ void dot4gl(const float* Xl,
                                       const float4* __restrict__ W,
                                       int k4, int col, float acc[4]) {
  const float4* X = (const float4*)Xl;
  #pragma unroll 2
  for (int kk = 0; kk < k4; ++kk) {
    float4 xv = X[kk];
    #pragma unroll
    for (int g = 0; g < 4; ++g) {
      float4 wv = W[kk * C4_ + g * H_ + col];
      acc[g] = fmaf(xv.x, wv.x, acc[g]);
      acc[g] = fmaf(xv.y, wv.y, acc[g]);
      acc[g] = fmaf(xv.z, wv.z, acc[g]);
      acc[g] = fmaf(xv.w, wv.w, acc[g]);
    }
  }
}

__device__ __forceinline__ float dot1l(const float* Xl,
                                       const float4* __restrict__ W,
                                       int k4, int stride) {
  const float4* X = (const float4*)Xl;
  float a = 0.0f;
  #pragma unroll 4
  for (int kk = 0; kk < k4; ++kk) {
    float4 xv = X[kk];
    float4 wv = W[kk * stride];
    a = fmaf(xv.x, wv.x, a); a = fmaf(xv.y, wv.y, a);
    a = fmaf(xv.z, wv.z, a); a = fmaf(xv.w, wv.w, a);
  }
  return a;
}

// repack row-major (K x C, leading dim ld) into k-interleaved float4 layout
__global__ void pack_k(const float* __restrict__ src, float* __restrict__ dst,
                       int K, int C, int ld) {
  int idx = blockIdx.x * 256 + threadIdx.x;
  if (idx >= K * C) return;
  int k = idx / C, c = idx - k * C;
  dst[(size_t)(k >> 2) * C * 4 + (size_t)c * 4 + (k & 3)] = src[(size_t)k * ld + c];
}

// transcriptions [b][u][n] -> [b][n][u] (w2's u-loop becomes contiguous float4s)
__global__ void pack_t(const float* __restrict__ src, float* __restrict__ dst) {
  int idx = blockIdx.x * 256 + threadIdx.x;
  if (idx >= B_ * U_ * N_) return;
  int b = idx >> 12, r = idx & 4095;
  int u = r >> 6, n = r & 63;
  dst[((size_t)b * N_ + n) * U_ + u] = src[((size_t)b * U_ + u) * N_ + n];
}

__global__ __launch_bounds__(NTHR, 2)
void net_kernel(Params p) {
  const int q = blockIdx.x;
  const int t = threadIdx.x;

  __shared__ float  s_buf[12288];   // staged X tiles
  __shared__ float  s_y[8][32];
  __shared__ float  s_k2[8][10];
  __shared__ float  s_kap[8][10];
  __shared__ double s_wf[8][66];

  if (q < NB_L0) {                                   // ---- layer 0 : 4 barriers ----
    const int bq = q >> 3, colg = q & 7;
    const int bl = t >> 6, cl = t & 63;
    const int b = bq * 8 + bl, col = colg * 64 + cl;
    float* sh = s_buf;            // h0(i-1): 8 x 512
    float* sw = s_buf + 4096;     // w(i-1):  8 x 64
    float creg = 0.0f;
    for (int i = 0; i < T_; ++i) {
      if (t == 0) {
        if (i >= 1) waitflag(FP(p.h0f, i - 1, bq), 8);
        if (i >= 8) waitflag(FP(p.outf, i - 8, bq), 1);
      }
      __syncthreads();                               // 1
      const int slp = (i - 1) & RB;
      stage4k(sh, &p.h0r[((size_t)slp * B_ + bq * 8) * H_], t);
      float acc[4];
      {
        const float* xs = &p.strokes[(b * T_ + i) * 3];
        float x0 = xs[0], x1 = xs[1], x2 = xs[2];
        #pragma unroll
        for (int g = 0; g < 4; ++g) {
          int cg = g * H_ + col;
          acc[g] = p.b0[cg] + x0 * p.W0[cg] + x1 * p.W0[C4_ + cg] + x2 * p.W0[2 * C4_ + cg];
        }
      }
      __syncthreads();                               // 2
      dot4gl(sh + bl * H_, p.PR0, 128, col, acc);
      if (t < 64) {    // wave0: lane0 polls wfl (hidden under dotR), wave stages w
        if (t == 0 && i >= 1) waitflag(FP(p.wfl, i - 1, bq), 1);
        stage512w(sw, &p.wr[((size_t)slp * B_ + bq * 8) * N_], t);
      }
      __syncthreads();                               // 3
      dot4gl(sw + bl * N_, p.PW0w, 16, col, acc);
      float cn = sigf(acc[1]) * creg + sigf(acc[0]) * tanhf(acc[2]);
      float hn = sigf(acc[3]) * tanhf(cn);
      creg = cn;
      cstoref(&p.h0r[((size_t)(i & RB) * B_ + b) * H_ + col], hn);
      __syncthreads();                               // 4 (drains ring stores)
      if (t == 0) postflag(FP(p.h0f, i, bq));
    }
  } else if (q < NB_L0 + NB_L1) {                    // ---- layer 1 : 4 barriers ----
    const int qq = q - NB_L0;
    const int bq = qq >> 3, colg = qq & 7;
    const int bl = t >> 6, cl = t & 63;
    const int b = bq * 8 + bl, col = colg * 64 + cl;
    float* sh0 = s_buf;           // h0(tt)
    float* sh1 = s_buf + 4096;    // h1(tt-1)
    float* sw  = s_buf + 8192;    // w(tt)
    float creg = 0.0f;
    for (int tt = 0; tt < T_; ++tt) {
      if (t == 0) {
        waitflag(FP(p.h0f, tt, bq), 8);
        if (tt >= 1) waitflag(FP(p.h1f, tt - 1, bq), 8);
        if (tt >= 7) waitflag(FP(p.outf, tt - 7, bq), 1);
      }
      __syncthreads();                               // 1
      const int sl = tt & RB, slp = (tt - 1) & RB;
      stage4k2(sh0, &p.h0r[((size_t)sl * B_ + bq * 8) * H_],
               sh1, &p.h1r[((size_t)slp * B_ + bq * 8) * H_], t);
      float acc[4];
      {
        const float* xs = &p.strokes[(b * T_ + tt) * 3];
        float x0 = xs[0], x1 = xs[1], x2 = xs[2];
        #pragma unroll
        for (int g = 0; g < 4; ++g) {
          int cg = g * H_ + col;
          acc[g] = p.b1[cg] + x0 * p.W1[576 * C4_ + cg] + x1 * p.W1[577 * C4_ + cg]
                            + x2 * p.W1[578 * C4_ + cg];
        }
      }
      __syncthreads();                               // 2
      dot4gl(sh0 + bl * H_, p.PH1, 128, col, acc);
      dot4gl(sh1 + bl * H_, p.PR1, 128, col, acc);
      if (t < 64) {    // wave0: wfl poll hidden under the big dots
        if (t == 0) waitflag(FP(p.wfl, tt, bq), 1);
        stage512w(sw, &p.wr[((size_t)sl * B_ + bq * 8) * N_], t);
      }
      __syncthreads();                               // 3
      dot4gl(sw + bl * N_, p.PW1w, 16, col, acc);
      float cn = sigf(acc[1]) * creg + sigf(acc[0]) * tanhf(acc[2]);
      float hn = sigf(acc[3]) * tanhf(cn);
      creg = cn;
      cstoref(&p.h1r[((size_t)sl * B_ + b) * H_ + col], hn);
      __syncthreads();                               // 4
      if (t == 0) postflag(FP(p.h1f, tt, bq));
    }
  } else if (q < NB_L0 + NB_L1 + NB_L2) {            // ---- layer 2 : 3 barriers ----
    const int qq = q - NB_L0 - NB_L1;
    const int bq = qq >> 3, colg = qq & 7;
    const int bl = t >> 6, cl = t & 63;
    const int b = bq * 8 + bl, col = colg * 64 + cl;
    float* sh1 = s_buf;           // h1(tt)
    float* sh2 = s_buf + 4096;    // h2(tt-1)
    float* sw  = s_buf + 8192;    // w(tt)
    float creg = 0.0f;
    for (int tt = 0; tt < T_; ++tt) {
      if (t == 0) {
        waitflag(FP(p.h1f, tt, bq), 8);
        waitflag(FP(p.wfl, tt, bq), 1);
        if (tt >= 1) waitflag(FP(p.h2f, tt - 1, bq), 8);
        if (tt >= 6) waitflag(FP(p.outf, tt - 6, bq), 1);
      }
      __syncthreads();                               // 1
      const int sl = tt & RB, slp = (tt - 1) & RB;
      stage4k2(sh1, &p.h1r[((size_t)sl * B_ + bq * 8) * H_],
               sh2, &p.h2r[((size_t)slp * B_ + bq * 8) * H_], t);
      stage512(sw, &p.wr[((size_t)sl * B_ + bq * 8) * N_], t);
      float acc[4];
      {
        const float* xs = &p.strokes[(b * T_ + tt) * 3];
        float x0 = xs[0], x1 = xs[1], x2 = xs[2];
        #pragma unroll
        for (int g = 0; g < 4; ++g) {
          int cg = g * H_ + col;
          acc[g] = p.b2[cg] + x0 * p.W2[576 * C4_ + cg] + x1 * p.W2[577 * C4_ + cg]
                            + x2 * p.W2[578 * C4_ + cg];
        }
      }
      __syncthreads();                               // 2
      dot4gl(sh1 + bl * H_, p.PH2, 128, col, acc);
      dot4gl(sw + bl * N_, p.PW2w, 16, col, acc);
      dot4gl(sh2 + bl * H_, p.PR2, 128, col, acc);
      float cn = sigf(acc[1]) * creg + sigf(acc[0]) * tanhf(acc[2]);
      float hn = sigf(acc[3]) * tanhf(cn);
      creg = cn;
      cstoref(&p.h2r[((size_t)sl * B_ + b) * H_ + col], hn);
      __syncthreads();                               // 3
      if (t == 0) postflag(FP(p.h2f, tt, bq));
    }
  } else if (q < NB_L0 + NB_L1 + NB_L2 + NB_OUT) {   // ---- output head : 3 barriers ----
    const int bq = q - NB_L0 - NB_L1 - NB_L2;
    const int bl = t >> 6, ol = t & 63;
    const int b = bq * 8 + bl;
    const int oo1 = ol;
    const bool v2 = (ol < O_ - 64);
    const int oo2 = v2 ? (ol + 64) : 0;
    float* sx0 = s_buf;
    float* sx1 = s_buf + 4096;
    float* sx2 = s_buf + 8192;
    for (int tt = 0; tt < T_; ++tt) {
      if (t == 0) {
        waitflag(FP(p.h0f, tt, bq), 8);
        waitflag(FP(p.h1f, tt, bq), 8);
        waitflag(FP(p.h2f, tt, bq), 8);
      }
      __syncthreads();                               // 1
      const int sl = tt & RB;
      {  // 3-tile fused stage: 6 x 16B per thread, two LLC round trips
        vf4 a0, c0, e0, a1, c1, e1;
        const vf4* A = (const vf4*)&p.h0r[((size_t)sl * B_ + bq * 8) * H_];
        const vf4* C = (const vf4*)&p.h1r[((size_t)sl * B_ + bq * 8) * H_];
        const vf4* E = (const vf4*)&p.h2r[((size_t)sl * B_ + bq * 8) * H_];
        cld3(A + t, C + t, E + t, a0, c0, e0);
        cld3(A + 512 + t, C + 512 + t, E + 512 + t, a1, c1, e1);
        *((vf4*)sx0 + t) = a0; *((vf4*)sx0 + 512 + t) = a1;
        *((vf4*)sx1 + t) = c0; *((vf4*)sx1 + 512 + t) = c1;
        *((vf4*)sx2 + t) = e0; *((vf4*)sx2 + 512 + t) = e1;
      }
      __syncthreads();                               // 2
      // early read-release: rings staged to LDS, producers may overwrite
      if (t == 0) postflag(FP(p.outf, tt, bq));
      const float* X0 = sx0 + bl * H_;
      const float* X1 = sx1 + bl * H_;
      const float* X2 = sx2 + bl * H_;
      float a1v = p.bo[oo1];
      a1v += dot1l(X0, p.PWo + oo1, 128, O_);
      a1v += dot1l(X1, p.PWo + (size_t)128 * O_ + oo1, 128, O_);
      a1v += dot1l(X2, p.PWo + (size_t)256 * O_ + oo1, 128, O_);
      float a2v = p.bo[oo2];
      a2v += dot1l(X0, p.PWo + oo2, 128, O_);
      a2v += dot1l(X1, p.PWo + (size_t)128 * O_ + oo2, 128, O_);
      a2v += dot1l(X2, p.PWo + (size_t)256 * O_ + oo2, 128, O_);
      __builtin_nontemporal_store(a1v, &p.outp[(size_t)(b * T_ + tt) * O_ + oo1]);
      if (v2) __builtin_nontemporal_store(a2v, &p.outp[(size_t)(b * T_ + tt) * O_ + oo2]);
      __syncthreads();                               // 3 (LDS reuse next iter)
    }
  } else {                                           // ---- attention (1 per bq) ----
    const int bq = q - NB_L0 - NB_L1 - NB_L2 - NB_OUT;
    const int lb = t >> 6, s = t & 63;    // 8 batches x 64 threads
    const int ub = bq * 8 + lb;
    for (int z = t; z < 80; z += NTHR) ((float*)s_kap)[z] = 0.0f;
    __syncthreads();
    for (int tt = 0; tt < T_; ++tt) {
      if (t == 0) waitflag(FP(p.h0f, tt, bq), 8);
      __syncthreads();                               // 1
      const int sl = tt & RB;
      {  // stage 8 rows (4096 floats): 2x16B per thread
        stage4k(s_buf, &p.h0r[((size_t)sl * B_ + bq * 8) * H_], t);
      }
      __syncthreads();                               // 2
      if (s < 30) {
        float a = p.bd[s] + dot1l(s_buf + lb * H_, p.PWd + s, 128, 30);
        float y = expf(a);
        s_y[lb][s] = y;
        if (s >= 20) {
          float k2 = s_kap[lb][s - 20] + y;
          s_kap[lb][s - 20] = k2;
          s_k2[lb][s - 20] = k2;
        }
      }
      __syncthreads();                               // 3
      // numpy-fp32 underflow-exact wfull (validated): u = s, plus s==0 does u=64
      for (int u = s; u < U_ + 1; u += 64) {
        double wf = 0.0;
        #pragma unroll
        for (int k = 0; k < KMIX; ++k) {
          float d32 = s_k2[lb][k] - (float)(u + 1);
          float sq  = d32 * d32;
          float m   = -(s_y[lb][10 + k] * sq);
          double e  = exp((double)m);
          double e32 = (e < 0x1p-126) ? 0.0 : (double)(float)e;
          wf += f32q((double)s_y[lb][k] * e32);
        }
        s_wf[lb][u] = wf;
      }
      __syncthreads();                               // 4
      {  // w2: one n per thread, contiguous float4 u-loads (transcrT)
        const float4* Tp = (const float4*)&p.transcrT[((size_t)ub * N_ + s) * U_];
        float a2 = 0.f;
        #pragma unroll
        for (int kk = 0; kk < 16; ++kk) {
          float4 tv = Tp[kk];
          a2 = fmaf((float)s_wf[lb][4 * kk],     tv.x, a2);
          a2 = fmaf((float)s_wf[lb][4 * kk + 1], tv.y, a2);
          a2 = fmaf((float)s_wf[lb][4 * kk + 2], tv.z, a2);
          a2 = fmaf((float)s_wf[lb][4 * kk + 3], tv.w, a2);
        }
        cstoref(&p.wr[((size_t)sl * B_ + ub) * N_ + s], a2);
      }
      __syncthreads();                               // 5 (drains wr stores)
      if (t == 0) postflag(FP(p.wfl, tt, bq));
      // argmax off the critical path (after wfl posted)
      if (s == 63) {
        int am = 0; double bv = s_wf[lb][0];
        for (int u = 1; u < U_ + 1; ++u) {
          double v = s_wf[lb][u];
          if (v > bv) { bv = v; am = u; }
        }
        __builtin_nontemporal_store((float)am, &p.attp[ub * T_ + tt]);
      }
    }
  }
}

extern "C" void kernel_launch(void* const* d_in, const int* in_sizes, int n_in,
                              void* d_out, int out_size, void* d_ws, size_t ws_size,
                              hipStream_t stream) {
  (void)in_sizes; (void)n_in; (void)out_size; (void)ws_size;
  const float* strokes = (const float*)d_in[0];
  const float* transcr = (const float*)d_in[1];
  const float* W0 = (const float*)d_in[2];
  const float* R0 = (const float*)d_in[3];
  const float* b0 = (const float*)d_in[4];
  const float* Wd = (const float*)d_in[5];
  const float* bd = (const float*)d_in[6];
  const float* W1 = (const float*)d_in[7];
  const float* R1 = (const float*)d_in[8];
  const float* b1 = (const float*)d_in[9];
  const float* W2 = (const float*)d_in[10];
  const float* R2 = (const float*)d_in[11];
  const float* b2 = (const float*)d_in[12];
  const float* Wo = (const float*)d_in[13];
  const float* bo = (const float*)d_in[14];

  float* ws = (float*)d_ws;
  size_t off = 0;
  float* h0r = ws + off; off += (size_t)RING * B_ * H_;
  float* h1r = ws + off; off += (size_t)RING * B_ * H_;
  float* h2r = ws + off; off += (size_t)RING * B_ * H_;
  float* wr  = ws + off; off += (size_t)RING * B_ * N_;
  const size_t FLAGN = (size_t)T_ * 8 * FS;
  int* h0f  = (int*)(ws + off); off += FLAGN;
  int* h1f  = (int*)(ws + off); off += FLAGN;
  int* h2f  = (int*)(ws + off); off += FLAGN;
  int* wfl  = (int*)(ws + off); off += FLAGN;
  int* outf = (int*)(ws + off); off += FLAGN;
  size_t stateFloats = off;
  float* PR0  = ws + off; off += (size_t)512 * 2048;
  float* PW0w = ws + off; off += (size_t)64 * 2048;
  float* PH1  = ws + off; off += (size_t)512 * 2048;
  float* PR1  = ws + off; off += (size_t)512 * 2048;
  float* PW1w = ws + off; off += (size_t)64 * 2048;
  float* PH2  = ws + off; off += (size_t)512 * 2048;
  float* PR2  = ws + off; off += (size_t)512 * 2048;
  float* PW2w = ws + off; off += (size_t)64 * 2048;
  float* PWo  = ws + off; off += (size_t)1536 * 121;
  float* PWd  = ws + off; off += (size_t)512 * 30;
  float* TT   = ws + off; off += (size_t)B_ * U_ * N_;

  // zero rings + flags (ws is poisoned 0xAA before every call)
  (void)hipMemsetAsync(d_ws, 0, stateFloats * sizeof(float), stream);

  auto packl = [&](const float* src, float* dst, int K, int C, int ld) {
    int n = K * C;
    pack_k<<<dim3((n + 255) / 256), dim3(256), 0, stream>>>(src, dst, K, C, ld);
  };
  packl(R0, PR0, 512, 2048, 2048);
  packl(W0 + 3 * 2048, PW0w, 64, 2048, 2048);
  packl(W1, PH1, 512, 2048, 2048);
  packl(R1, PR1, 512, 2048, 2048);
  packl(W1 + 512 * 2048, PW1w, 64, 2048, 2048);
  packl(W2, PH2, 512, 2048, 2048);
  packl(R2, PR2, 512, 2048, 2048);
  packl(W2 + 512 * 2048, PW2w, 64, 2048, 2048);
  packl(Wo, PWo, 1536, 121, 121);
  packl(Wd, PWd, 512, 30, 30);
  pack_t<<<dim3((B_ * U_ * N_ + 255) / 256), dim3(256), 0, stream>>>(transcr, TT);

  Params p;
  p.strokes = strokes; p.transcr = transcr; p.transcrT = TT;
  p.W0 = W0; p.b0 = b0; p.bd = bd;
  p.W1 = W1; p.b1 = b1; p.W2 = W2; p.b2 = b2; p.bo = bo;
  p.PR0 = (const float4*)PR0; p.PW0w = (const float4*)PW0w;
  p.PH1 = (const float4*)PH1; p.PR1 = (const float4*)PR1; p.PW1w = (const float4*)PW1w;
  p.PH2 = (const float4*)PH2; p.PR2 = (const float4*)PR2; p.PW2w = (const float4*)PW2w;
  p.PWo = (const float4*)PWo; p.PWd = (const float4*)PWd;
  p.h0r = h0r; p.h1r = h1r; p.h2r = h2r; p.wr = wr;
  p.h0f = h0f; p.h1f = h1f; p.h2f = h2f; p.wfl = wfl; p.outf = outf;
  p.outp = (float*)d_out;
  p.attp = (float*)d_out + (size_t)B_ * T_ * O_;

  void* args[] = { (void*)&p };
  (void)hipLaunchCooperativeKernel((const void*)net_kernel, dim3(NBLK), dim3(NTHR),
                                   args, 0, stream);
}